// Round 17
// baseline (339.644 us; speedup 1.0000x reference)
//
#include <hip/hip_runtime.h>
#include <hip/hip_bf16.h>

#define DEV static __device__ __forceinline__

constexpr int F1 = 128;   // input features
constexpr int H1 = 8;     // heads layer1
constexpr int C  = 64;    // channels per head
constexpr int B  = 64;    // graphs
constexpr int K  = 10;    // classes
constexpr float NEG = 0.2f;

typedef __attribute__((ext_vector_type(8))) short short8;
typedef __attribute__((ext_vector_type(4))) float floatx4;

DEV float b2f(__hip_bfloat16 x) { return __bfloat162float(x); }
DEV float elu1(float v) { return v > 0.f ? v : (__expf(v) - 1.f); }
DEV unsigned short f2bbits(float f) {
  __hip_bfloat16 b = __float2bfloat16(f);
  return *(unsigned short*)&b;
}
DEV float blo(unsigned u) { return __uint_as_float(u << 16); }
DEV float bhi(unsigned u) { return __uint_as_float(u & 0xffff0000u); }
DEV float bu(unsigned short u) { return __uint_as_float(((unsigned)u) << 16); }
DEV unsigned pack2(float lo, float hi) {
  return (unsigned)f2bbits(lo) | ((unsigned)f2bbits(hi) << 16);
}

// Self-detection: thread 0 samples 128 even-index bf16 reinterps of x.
DEV int detect_dev(const void* xraw, int* lds) {
  if (threadIdx.x == 0) {
    const __hip_bfloat16* xb = (const __hip_bfloat16*)xraw;
    int bad = 0;
    for (int i = 0; i < 128; ++i) {
      float v = b2f(xb[2 * i]);
      if (!(fabsf(v) < 1e4f)) bad++;
    }
    *lds = (bad < 13) ? 1 : 0;     // 1 = bf16, 0 = f32
  }
  __syncthreads();
  return *lds;
}

#define CVT(p, i) (isbf ? b2f(((const __hip_bfloat16*)(p))[i]) : ((const float*)(p))[i])

// ---------- fused prep ----------
__global__ void fused_prep_kernel(const void* x_raw, const void* w1raw,
                                  const void* as1r, const void* ad1r, const void* b1r,
                                  const void* w2raw,
                                  const void* as2r, const void* ad2r, const void* b2r,
                                  const void* l1wr, const void* l1br,
                                  const void* l2wr, const void* l2br,
                                  unsigned short* __restrict__ xbf,
                                  unsigned short* __restrict__ w1frag,
                                  unsigned short* __restrict__ w2frag,
                                  float* __restrict__ wts,
                                  int* __restrict__ deg,
                                  float* __restrict__ pooled,
                                  int nX, int N) {
  __shared__ int fl;
  int isbf = detect_dev(x_raw, &fl);
  int gid = blockIdx.x * 256 + threadIdx.x;
  int stride = gridDim.x * 256;

  if (isbf) {
    const unsigned short* src = (const unsigned short*)x_raw;
    for (int i = gid; i < nX; i += stride) xbf[i] = src[i];
  } else {
    const float* src = (const float*)x_raw;
    for (int i = gid; i < nX; i += stride) xbf[i] = f2bbits(src[i]);
  }
  for (int i = gid; i < 512;  i += stride) wts[0    + i] = CVT(as1r, i);
  for (int i = gid; i < 512;  i += stride) wts[512  + i] = CVT(ad1r, i);
  for (int i = gid; i < 512;  i += stride) wts[1024 + i] = CVT(b1r, i);
  for (int i = gid; i < 64;   i += stride) wts[1536 + i] = CVT(as2r, i);
  for (int i = gid; i < 64;   i += stride) wts[1600 + i] = CVT(ad2r, i);
  for (int i = gid; i < 64;   i += stride) wts[1664 + i] = CVT(b2r, i);
  for (int i = gid; i < 4096; i += stride) wts[1728 + i] = CVT(l1wr, i);
  for (int i = gid; i < 64;   i += stride) wts[5824 + i] = CVT(l1br, i);
  for (int i = gid; i < 640;  i += stride) wts[5888 + i] = CVT(l2wr, i);
  for (int i = gid; i < 10;   i += stride) wts[6528 + i] = CVT(l2br, i);
  for (int t = gid; t < 8192; t += stride) {
    int lane = t & 63, ks = (t >> 6) & 3, nt = t >> 8;
    for (int j = 0; j < 8; ++j) {
      int k = ks * 32 + (lane >> 4) * 8 + j;
      int n = nt * 16 + (lane & 15);
      w1frag[t * 8 + j] = f2bbits(CVT(w1raw, k * 512 + n));
    }
  }
  for (int t = gid; t < 4096; t += stride) {
    int lane = t & 63, nt = (t >> 6) & 3, ks = t >> 8;
    for (int j = 0; j < 8; ++j) {
      int k = ks * 32 + (lane >> 4) * 8 + j;
      int n = nt * 16 + (lane & 15);
      w2frag[t * 8 + j] = f2bbits(CVT(w2raw, k * 64 + n));
    }
  }
  for (int i = gid; i < N; i += stride) deg[i] = 0;
  for (int i = gid; i < B * C; i += stride) pooled[i] = 0.f;
}

// ---------- degree count ----------
__global__ void deg_count_kernel(const int* __restrict__ ei, int E, int Etot,
                                 int* __restrict__ deg) {
  int e = blockIdx.x * blockDim.x + threadIdx.x;
  if (e >= Etot) return;
  int d = (e < E) ? ei[E + e] : e - E;
  atomicAdd(&deg[d], 1);
}

// ---------- CSR scans ----------
__global__ void scan_block_kernel(const int* __restrict__ deg,
                                  int* __restrict__ local,
                                  int* __restrict__ bsum, int N) {
  __shared__ int tmp[256];
  int t = threadIdx.x;
  int i = blockIdx.x * 256 + t;
  int v = (i < N) ? deg[i] : 0;
  tmp[t] = v;
  __syncthreads();
  for (int off = 1; off < 256; off <<= 1) {
    int u = (t >= off) ? tmp[t - off] : 0;
    __syncthreads();
    tmp[t] += u;
    __syncthreads();
  }
  if (i < N) local[i] = tmp[t] - v;
  if (t == 255) bsum[blockIdx.x] = tmp[255];
}

__global__ void scan_finish_kernel(const int* __restrict__ local,
                                   const int* __restrict__ bsum, int nb,
                                   int* __restrict__ rowptr,
                                   int* __restrict__ cursor, int N, int Etot) {
  __shared__ int tmp[256];
  __shared__ int offs;
  int t = threadIdx.x;
  int v0 = (t < nb) ? bsum[t] : 0;
  tmp[t] = v0;
  __syncthreads();
  for (int off = 1; off < 256; off <<= 1) {
    int u = (t >= off) ? tmp[t - off] : 0;
    __syncthreads();
    tmp[t] += u;
    __syncthreads();
  }
  if (t == (int)blockIdx.x) offs = tmp[t] - v0;
  __syncthreads();
  int i = blockIdx.x * 256 + t;
  if (i < N) {
    int r = local[i] + offs;
    rowptr[i] = r;
    cursor[i] = r;
  }
  if (i == 0) rowptr[N] = Etot;
}

// ---------- layer-1 MFMA GEMM (LDS-staged coalesced h1 writes) + csr_fill ----------
// blocks [0, gb): 64-row MFMA GEMM tiles; blocks [gb, ...): CSR fill.
__global__ __launch_bounds__(256) void gemm1_fill_kernel(
    const unsigned short* __restrict__ xbf,     // N x 128 bf16
    const unsigned short* __restrict__ W1frag,  // [32][4][64][8] bf16
    const float* __restrict__ att_src,          // 512
    const float* __restrict__ att_dst,
    unsigned short* __restrict__ h1,            // N x 512 bf16
    float* __restrict__ a_s, float* __restrict__ a_d,   // N x 8
    const int* __restrict__ ei, int E, int Etot,
    int* __restrict__ cursor, int* __restrict__ col,
    int gb, int N) {
  // 17408 B: x-tile staging (64x136 halves), then reused as h1-tile staging.
  __shared__ __align__(16) unsigned short Xls[64 * 136];
  int t = threadIdx.x;

  if ((int)blockIdx.x >= gb) {                  // csr_fill blocks
    int e = ((int)blockIdx.x - gb) * 256 + t;
    if (e < Etot) {
      int s, d;
      if (e < E) { s = ei[e]; d = ei[E + e]; } else { s = d = e - E; }
      int pos = atomicAdd(&cursor[d], 1);
      col[pos] = s;
    }
    return;
  }

  int w = t >> 6, lane = t & 63;
  int quad = lane >> 4, l16 = lane & 15;
  int blkbase = blockIdx.x * 64;
  int rowbase = blkbase + w * 16;

  for (int idx = t; idx < 1024; idx += 256) {
    int row = idx >> 4, c = idx & 15;
    int rg = blkbase + row; if (rg >= N) rg = N - 1;
    *(uint4*)&Xls[row * 136 + c * 8] =
        *(const uint4*)(xbf + (size_t)rg * 128 + c * 8);
  }
  __syncthreads();

  short8 afr[4];
  {
    int rl = w * 16 + l16;
#pragma unroll
    for (int ks = 0; ks < 4; ++ks)
      afr[ks] = *(const short8*)&Xls[rl * 136 + ks * 32 + quad * 8];
  }

  for (int hp = 0; hp < 4; ++hp) {
    floatx4 acc[8] = {};
    const unsigned short* Bp = W1frag + (size_t)hp * 16384;
#pragma unroll
    for (int nt = 0; nt < 8; ++nt)
#pragma unroll
      for (int ks = 0; ks < 4; ++ks) {
        short8 b = *(const short8*)&Bp[((nt * 4 + ks) * 64 + lane) * 8];
        acc[nt] = __builtin_amdgcn_mfma_f32_16x16x32_bf16(afr[ks], b, acc[nt], 0, 0, 0);
      }

    // attention-coef partial reductions (from registers)
    float asw[8], adw[8];
#pragma unroll
    for (int nt = 0; nt < 8; ++nt) {
      asw[nt] = att_src[hp * 128 + nt * 16 + l16];
      adw[nt] = att_dst[hp * 128 + nt * 16 + l16];
    }
    float ps[2][4] = {}, pd[2][4] = {};
#pragma unroll
    for (int nt = 0; nt < 8; ++nt) {
      int hl = nt >> 2;
#pragma unroll
      for (int r = 0; r < 4; ++r) {
        ps[hl][r] += acc[nt][r] * asw[nt];
        pd[hl][r] += acc[nt][r] * adw[nt];
      }
    }
#pragma unroll
    for (int hl = 0; hl < 2; ++hl)
#pragma unroll
      for (int r = 0; r < 4; ++r) {
        float p = ps[hl][r], q = pd[hl][r];
#pragma unroll
        for (int off = 1; off < 16; off <<= 1) {
          p += __shfl_xor(p, off);
          q += __shfl_xor(q, off);
        }
        int row = rowbase + quad * 4 + r;
        if (l16 == 0 && row < N) {
          a_s[(size_t)row * 8 + hp * 2 + hl] = p;
          a_d[(size_t)row * 8 + hp * 2 + hl] = q;
        }
      }

    // stage h1 tile in LDS (scattered ushort), then coalesced uint4 writes.
    __syncthreads();   // afr reads (hp==0) / previous hp's tile reads done
#pragma unroll
    for (int nt = 0; nt < 8; ++nt)
#pragma unroll
      for (int r = 0; r < 4; ++r) {
        int rl = w * 16 + quad * 4 + r;
        Xls[rl * 136 + nt * 16 + l16] = f2bbits(acc[nt][r]);
      }
    __syncthreads();
    for (int j = 0; j < 4; ++j) {
      int idx = t + j * 256;          // 1024 chunks: row = idx>>4, c8 = idx&15
      int row = idx >> 4, c8 = idx & 15;
      int rg = blkbase + row;
      if (rg < N)
        *(uint4*)&h1[(size_t)rg * 512 + hp * 128 + c8 * 8] =
            *(const uint4*)&Xls[row * 136 + c8 * 8];
    }
  }
}

// ---------- layer 2: MFMA bf16 GEMM, 64-row blocks, B-frags from L2 ----------
__global__ __launch_bounds__(256) void gemm2_mfma_kernel(
    const unsigned short* __restrict__ x2bf,    // N x 512 bf16
    const unsigned short* __restrict__ W2frag,  // [16ks][4nt][64][8] bf16
    const float* __restrict__ att_src,          // 64
    const float* __restrict__ att_dst,
    unsigned short* __restrict__ h2,            // N x 64 bf16
    float* __restrict__ a_s, float* __restrict__ a_d,  // N
    int N) {
  int t = threadIdx.x;
  int w = t >> 6, lane = t & 63;
  int quad = lane >> 4, l16 = lane & 15;
  int rowbase = blockIdx.x * 64 + w * 16;

  floatx4 acc[4] = {};
  int r0 = rowbase + l16; if (r0 >= N) r0 = N - 1;
  const unsigned short* p0 = x2bf + (size_t)r0 * 512 + quad * 8;
#pragma unroll
  for (int ks = 0; ks < 16; ++ks) {
    short8 a0 = *(const short8*)(p0 + ks * 32);
#pragma unroll
    for (int nt = 0; nt < 4; ++nt) {
      short8 b = *(const short8*)&W2frag[((ks * 4 + nt) * 64 + lane) * 8];
      acc[nt] = __builtin_amdgcn_mfma_f32_16x16x32_bf16(a0, b, acc[nt], 0, 0, 0);
    }
  }

  float asw[4], adw[4];
#pragma unroll
  for (int nt = 0; nt < 4; ++nt) {
    asw[nt] = att_src[nt * 16 + l16];
    adw[nt] = att_dst[nt * 16 + l16];
  }
  float ps[4] = {}, pd[4] = {};
#pragma unroll
  for (int nt = 0; nt < 4; ++nt)
#pragma unroll
    for (int r = 0; r < 4; ++r) {
      float v = acc[nt][r];
      int row = rowbase + quad * 4 + r;
      if (row < N) h2[(size_t)row * 64 + nt * 16 + l16] = f2bbits(v);
      ps[r] += v * asw[nt];
      pd[r] += v * adw[nt];
    }
#pragma unroll
  for (int r = 0; r < 4; ++r) {
    float p = ps[r], q = pd[r];
#pragma unroll
    for (int off = 1; off < 16; off <<= 1) {
      p += __shfl_xor(p, off);
      q += __shfl_xor(q, off);
    }
    int row = rowbase + quad * 4 + r;
    if (l16 == 0 && row < N) {
      a_s[row] = p;
      a_d[row] = q;
    }
  }
}

// ---------- single-pass GAT aggregation, H=8, bf16 in AND out ----------
__global__ void gat_agg8_kernel(const int* __restrict__ rowptr,
                                const int* __restrict__ col,
                                const float* __restrict__ a_s,
                                const float* __restrict__ a_d,
                                const unsigned short* __restrict__ hfeat,
                                const float* __restrict__ bias,
                                unsigned short* __restrict__ out, int N) {
  int wave = threadIdx.x >> 6, lane = threadIdx.x & 63;
  int d = blockIdx.x * 4 + wave;
  if (d >= N) return;
  int beg = rowptr[d], end = rowptr[d + 1];
  int hh = lane >> 3;
  float adh = a_d[(size_t)d * 8 + hh];

  const uint4* hf = (const uint4*)hfeat;
  float acc[8] = {};
  float wsum = 0.f;
#pragma unroll 4
  for (int i = beg; i < end; ++i) {
    int s = col[i];                          // wave-uniform
    float e = a_s[(size_t)s * 8 + hh] + adh;
    e = e > 0.f ? e : NEG * e;
    float wv = __expf(e);
    wsum += wv;
    uint4 q = hf[(size_t)s * 64 + lane];
    acc[0] += wv * blo(q.x); acc[1] += wv * bhi(q.x);
    acc[2] += wv * blo(q.y); acc[3] += wv * bhi(q.y);
    acc[4] += wv * blo(q.z); acc[5] += wv * bhi(q.z);
    acc[6] += wv * blo(q.w); acc[7] += wv * bhi(q.w);
  }
  float winv = 1.f / (wsum + 1e-16f);
  const float4* b4 = (const float4*)bias;
  float4 b0 = b4[2 * lane], b1 = b4[2 * lane + 1];
  float v0 = elu1(acc[0] * winv + b0.x), v1 = elu1(acc[1] * winv + b0.y);
  float v2 = elu1(acc[2] * winv + b0.z), v3 = elu1(acc[3] * winv + b0.w);
  float v4 = elu1(acc[4] * winv + b1.x), v5 = elu1(acc[5] * winv + b1.y);
  float v6 = elu1(acc[6] * winv + b1.z), v7 = elu1(acc[7] * winv + b1.w);
  uint4 o;
  o.x = pack2(v0, v1); o.y = pack2(v2, v3);
  o.z = pack2(v4, v5); o.w = pack2(v6, v7);
  ((uint4*)out)[(size_t)d * 64 + lane] = o;   // channels 8*lane..+7
}

// H=1, quarter-wave edge grouping.
__global__ void gat_agg1_kernel(const int* __restrict__ rowptr,
                                const int* __restrict__ col,
                                const float* __restrict__ a_s,
                                const float* __restrict__ a_d,
                                const unsigned short* __restrict__ hfeat,
                                const float* __restrict__ bias,
                                unsigned short* __restrict__ out, int N) {
  int wave = threadIdx.x >> 6, lane = threadIdx.x & 63;
  int d = blockIdx.x * 4 + wave;
  if (d >= N) return;
  int beg = rowptr[d], end = rowptr[d + 1];
  int qg = lane >> 4, l16 = lane & 15;
  float adv = a_d[d];
  const uint2* hfu = (const uint2*)hfeat;
  float acc[4] = {};
  float wsum = 0.f;
#pragma unroll 2
  for (int i = beg + qg; i < end; i += 4) {
    int s = col[i];
    float v = a_s[s] + adv;
    v = v > 0.f ? v : NEG * v;
    float wv = __expf(v);
    wsum += wv;
    uint2 u = hfu[(size_t)s * 16 + l16];
    acc[0] += wv * blo(u.x); acc[1] += wv * bhi(u.x);
    acc[2] += wv * blo(u.y); acc[3] += wv * bhi(u.y);
  }
#pragma unroll
  for (int off = 16; off <= 32; off <<= 1) {
#pragma unroll
    for (int j = 0; j < 4; ++j) acc[j] += __shfl_xor(acc[j], off);
    wsum += __shfl_xor(wsum, off);
  }
  float winv = 1.f / (wsum + 1e-16f);
  float4 bb = ((const float4*)bias)[l16];
  float r0 = elu1(acc[0] * winv + bb.x), r1 = elu1(acc[1] * winv + bb.y);
  float r2 = elu1(acc[2] * winv + bb.z), r3 = elu1(acc[3] * winv + bb.w);
  if (qg == 0) {
    uint2 o; o.x = pack2(r0, r1); o.y = pack2(r2, r3);
    ((uint2*)out)[(size_t)d * 16 + l16] = o;
  }
}

// ---------- pooling: 16 nodes per wave ----------
__global__ void pool_kernel(const unsigned short* __restrict__ out2,
                            const int* __restrict__ batch,
                            float* __restrict__ pooled, int N) {
  int wave = threadIdx.x >> 6, lane = threadIdx.x & 63;
  int seg = blockIdx.x * 4 + wave;
  int start = seg * 16;
  if (start >= N) return;
  int end = min(start + 16, N);
  int cur = batch[start];
  float acc = 0.f;
  for (int n = start; n < end; ++n) {
    int bn = batch[n];
    if (bn != cur) {
      unsafeAtomicAdd(&pooled[cur * 64 + lane], acc);
      acc = 0.f; cur = bn;
    }
    acc += bu(out2[(size_t)n * 64 + lane]);
  }
  unsafeAtomicAdd(&pooled[cur * 64 + lane], acc);
}

// ---------- MLP head + log_softmax: one block (one wave) per graph ----------
__global__ void head_kernel(const float* __restrict__ pooled,
                            const float* __restrict__ lin1_w,
                            const float* __restrict__ lin1_b,
                            const float* __restrict__ lin2_w,
                            const float* __restrict__ lin2_b,
                            const void* __restrict__ x_raw,
                            void* __restrict__ outv) {
  __shared__ float P[C];
  __shared__ float Zs[C];
  __shared__ float Ls[K];
  __shared__ float lse_s;
  __shared__ int fl;
  int isbf = detect_dev(x_raw, &fl);
  int g = blockIdx.x, t = threadIdx.x;   // 64 threads
  P[t] = pooled[g * C + t];
  __syncthreads();
  float acc = lin1_b[t];
  for (int k = 0; k < C; ++k) acc += P[k] * lin1_w[k * C + t];
  Zs[t] = elu1(acc);
  __syncthreads();
  if (t < K) {
    float a = lin2_b[t];
    for (int k = 0; k < C; ++k) a += Zs[k] * lin2_w[k * K + t];
    Ls[t] = a;
  }
  __syncthreads();
  if (t == 0) {
    float mx = -1e30f;
    for (int c = 0; c < K; ++c) mx = fmaxf(mx, Ls[c]);
    float s = 0.f;
    for (int c = 0; c < K; ++c) s += __expf(Ls[c] - mx);
    lse_s = mx + __logf(s);
  }
  __syncthreads();
  if (t < K) {
    float val = Ls[t] - lse_s;
    if (isbf) ((__hip_bfloat16*)outv)[g * K + t] = __float2bfloat16(val);
    else      ((float*)outv)[g * K + t] = val;
  }
}

extern "C" void kernel_launch(void* const* d_in, const int* in_sizes, int n_in,
                              void* d_out, int out_size, void* d_ws, size_t ws_size,
                              hipStream_t stream) {
  const void* x_raw = d_in[0];
  const int*  ei    = (const int*)d_in[1];
  const int*  batch = (const int*)d_in[2];

  const int N    = in_sizes[2];
  const int E    = in_sizes[1] / 2;
  const int Etot = E + N;
  const int nb   = (N + 255) / 256;

  float* ws   = (float*)d_ws;
  size_t off  = 0;

  float* wts = ws + off; off += 6544;
  float* as1w = wts + 0;
  float* ad1w = wts + 512;
  float* b1w  = wts + 1024;
  float* as2w = wts + 1536;
  float* ad2w = wts + 1600;
  float* b2w  = wts + 1664;
  float* l1w  = wts + 1728;
  float* l1b  = wts + 5824;
  float* l2w  = wts + 5888;
  float* l2b  = wts + 6528;

  unsigned short* xbf    = (unsigned short*)(ws + off); off += (size_t)N * 64;
  unsigned short* w1frag = (unsigned short*)(ws + off); off += 32768;
  unsigned short* w2frag = (unsigned short*)(ws + off); off += 16384;
  unsigned short* h1bf   = (unsigned short*)(ws + off); off += (size_t)N * 256;
  unsigned short* out1bf = (unsigned short*)(ws + off); off += (size_t)N * 256;
  unsigned short* h2bf   = (unsigned short*)(ws + off); off += (size_t)N * 32;
  unsigned short* out2bf = (unsigned short*)(ws + off); off += (size_t)N * 32;
  float* as1  = ws + off; off += (size_t)N * H1;
  float* ad1  = ws + off; off += (size_t)N * H1;
  float* as2  = ws + off; off += (size_t)N;
  float* ad2  = ws + off; off += (size_t)N;
  float* pooled = ws + off; off += (size_t)B * C;

  int* ibase  = (int*)(ws + off);
  int* deg    = ibase;                 ibase += N;
  int* cursor = ibase;                 ibase += N;
  int* rowptr = ibase;                 ibase += N + 1;
  int* locals = ibase;                 ibase += N;
  int* bsum   = ibase;                 ibase += 256;
  int* col    = ibase;                 ibase += Etot;

  // ---- prep ----
  fused_prep_kernel<<<1024, 256, 0, stream>>>(
      x_raw, d_in[3], d_in[4], d_in[5], d_in[6], d_in[7], d_in[8], d_in[9],
      d_in[10], d_in[11], d_in[12], d_in[13], d_in[14],
      xbf, w1frag, w2frag, wts, deg, pooled, in_sizes[0], N);

  // ---- CSR: deg + scans ----
  deg_count_kernel<<<(Etot + 255) / 256, 256, 0, stream>>>(ei, E, Etot, deg);
  scan_block_kernel<<<nb, 256, 0, stream>>>(deg, locals, bsum, N);
  scan_finish_kernel<<<nb, 256, 0, stream>>>(locals, bsum, nb, rowptr, cursor, N, Etot);

  // ---- layer-1 GEMM + csr_fill (one dispatch, independent halves) ----
  {
    int gb = (N + 63) / 64;
    int fb = (Etot + 255) / 256;
    gemm1_fill_kernel<<<gb + fb, 256, 0, stream>>>(xbf, w1frag, as1w, ad1w,
                                                   h1bf, as1, ad1,
                                                   ei, E, Etot, cursor, col, gb, N);
  }

  // ---- layer 1 aggregation ----
  gat_agg8_kernel<<<(N + 3) / 4, 256, 0, stream>>>(rowptr, col, as1, ad1, h1bf, b1w, out1bf, N);

  // ---- layer 2 ----
  gemm2_mfma_kernel<<<(N + 63) / 64, 256, 0, stream>>>(out1bf, w2frag, as2w, ad2w,
                                                       h2bf, as2, ad2, N);
  gat_agg1_kernel<<<(N + 3) / 4, 256, 0, stream>>>(rowptr, col, as2, ad2, h2bf, b2w, out2bf, N);

  // ---- pool + head ----
  pool_kernel<<<(N + 63) / 64, 256, 0, stream>>>(out2bf, batch, pooled, N);
  head_kernel<<<B, 64, 0, stream>>>(pooled, l1w, l1b, l2w, l2b, x_raw, (void*)d_out);
}

// Round 18
// 304.529 us; speedup vs baseline: 1.1153x; 1.1153x over previous
//
#include <hip/hip_runtime.h>
#include <hip/hip_bf16.h>

#define DEV static __device__ __forceinline__

constexpr int F1 = 128;   // input features
constexpr int H1 = 8;     // heads layer1
constexpr int C  = 64;    // channels per head
constexpr int B  = 64;    // graphs
constexpr int K  = 10;    // classes
constexpr float NEG = 0.2f;

typedef __attribute__((ext_vector_type(8))) short short8;
typedef __attribute__((ext_vector_type(4))) float floatx4;

DEV float b2f(__hip_bfloat16 x) { return __bfloat162float(x); }
DEV float elu1(float v) { return v > 0.f ? v : (__expf(v) - 1.f); }
DEV unsigned short f2bbits(float f) {
  __hip_bfloat16 b = __float2bfloat16(f);
  return *(unsigned short*)&b;
}
DEV float blo(unsigned u) { return __uint_as_float(u << 16); }
DEV float bhi(unsigned u) { return __uint_as_float(u & 0xffff0000u); }
DEV float bu(unsigned short u) { return __uint_as_float(((unsigned)u) << 16); }
DEV unsigned pack2(float lo, float hi) {
  return (unsigned)f2bbits(lo) | ((unsigned)f2bbits(hi) << 16);
}

// h1 PERMUTED layout: position p = hp*128 + l16*8 + nt  <->  natural channel
// c = hp*128 + nt*16 + l16  (hp<4, l16<16, nt<8). Dot products over the
// contraction dim are permutation-invariant; W2frag k-rows and b1 are
// permuted to match. Head of position p = (p>>7)*2 + ((p&7)>>2).

// Self-detection: thread 0 samples 128 even-index bf16 reinterps of x.
DEV int detect_dev(const void* xraw, int* lds) {
  if (threadIdx.x == 0) {
    const __hip_bfloat16* xb = (const __hip_bfloat16*)xraw;
    int bad = 0;
    for (int i = 0; i < 128; ++i) {
      float v = b2f(xb[2 * i]);
      if (!(fabsf(v) < 1e4f)) bad++;
    }
    *lds = (bad < 13) ? 1 : 0;     // 1 = bf16, 0 = f32
  }
  __syncthreads();
  return *lds;
}

#define CVT(p, i) (isbf ? b2f(((const __hip_bfloat16*)(p))[i]) : ((const float*)(p))[i])

// ---------- fused prep ----------
__global__ void fused_prep_kernel(const void* x_raw, const void* w1raw,
                                  const void* as1r, const void* ad1r, const void* b1r,
                                  const void* w2raw,
                                  const void* as2r, const void* ad2r, const void* b2r,
                                  const void* l1wr, const void* l1br,
                                  const void* l2wr, const void* l2br,
                                  unsigned short* __restrict__ xbf,
                                  unsigned short* __restrict__ w1frag,
                                  unsigned short* __restrict__ w2frag,
                                  float* __restrict__ wts,
                                  int* __restrict__ deg,
                                  float* __restrict__ pooled,
                                  int nX, int N) {
  __shared__ int fl;
  int isbf = detect_dev(x_raw, &fl);
  int gid = blockIdx.x * 256 + threadIdx.x;
  int stride = gridDim.x * 256;

  if (isbf) {
    const unsigned short* src = (const unsigned short*)x_raw;
    for (int i = gid; i < nX; i += stride) xbf[i] = src[i];
  } else {
    const float* src = (const float*)x_raw;
    for (int i = gid; i < nX; i += stride) xbf[i] = f2bbits(src[i]);
  }
  for (int i = gid; i < 512;  i += stride) wts[0    + i] = CVT(as1r, i);
  for (int i = gid; i < 512;  i += stride) wts[512  + i] = CVT(ad1r, i);
  // b1 stored PERMUTED: wts[1024 + p] = b1[c_nat(p)]
  for (int i = gid; i < 512;  i += stride) {
    int hp = i >> 7, l16 = (i >> 3) & 15, nt = i & 7;
    int c = hp * 128 + nt * 16 + l16;
    wts[1024 + i] = CVT(b1r, c);
  }
  for (int i = gid; i < 64;   i += stride) wts[1536 + i] = CVT(as2r, i);
  for (int i = gid; i < 64;   i += stride) wts[1600 + i] = CVT(ad2r, i);
  for (int i = gid; i < 64;   i += stride) wts[1664 + i] = CVT(b2r, i);
  for (int i = gid; i < 4096; i += stride) wts[1728 + i] = CVT(l1wr, i);
  for (int i = gid; i < 64;   i += stride) wts[5824 + i] = CVT(l1br, i);
  for (int i = gid; i < 640;  i += stride) wts[5888 + i] = CVT(l2wr, i);
  for (int i = gid; i < 10;   i += stride) wts[6528 + i] = CVT(l2br, i);
  for (int t = gid; t < 8192; t += stride) {
    int lane = t & 63, ks = (t >> 6) & 3, nt = t >> 8;
    for (int j = 0; j < 8; ++j) {
      int k = ks * 32 + (lane >> 4) * 8 + j;
      int n = nt * 16 + (lane & 15);
      w1frag[t * 8 + j] = f2bbits(CVT(w1raw, k * 512 + n));
    }
  }
  // W2frag with PERMUTED k: k index in fragment = position p; fetch W2[c_nat(p)]
  for (int t = gid; t < 4096; t += stride) {
    int lane = t & 63, nt = (t >> 6) & 3, ks = t >> 8;
    for (int j = 0; j < 8; ++j) {
      int p = ks * 32 + (lane >> 4) * 8 + j;          // permuted position
      int hp = p >> 7, pl16 = (p >> 3) & 15, pnt = p & 7;
      int k = hp * 128 + pnt * 16 + pl16;             // natural channel
      int n = nt * 16 + (lane & 15);
      w2frag[t * 8 + j] = f2bbits(CVT(w2raw, k * 64 + n));
    }
  }
  for (int i = gid; i < N; i += stride) deg[i] = 0;
  for (int i = gid; i < B * C; i += stride) pooled[i] = 0.f;
}

// ---------- degree count ----------
__global__ void deg_count_kernel(const int* __restrict__ ei, int E, int Etot,
                                 int* __restrict__ deg) {
  int e = blockIdx.x * blockDim.x + threadIdx.x;
  if (e >= Etot) return;
  int d = (e < E) ? ei[E + e] : e - E;
  atomicAdd(&deg[d], 1);
}

// ---------- CSR scans ----------
__global__ void scan_block_kernel(const int* __restrict__ deg,
                                  int* __restrict__ local,
                                  int* __restrict__ bsum, int N) {
  __shared__ int tmp[256];
  int t = threadIdx.x;
  int i = blockIdx.x * 256 + t;
  int v = (i < N) ? deg[i] : 0;
  tmp[t] = v;
  __syncthreads();
  for (int off = 1; off < 256; off <<= 1) {
    int u = (t >= off) ? tmp[t - off] : 0;
    __syncthreads();
    tmp[t] += u;
    __syncthreads();
  }
  if (i < N) local[i] = tmp[t] - v;
  if (t == 255) bsum[blockIdx.x] = tmp[255];
}

__global__ void scan_finish_kernel(const int* __restrict__ local,
                                   const int* __restrict__ bsum, int nb,
                                   int* __restrict__ rowptr,
                                   int* __restrict__ cursor, int N, int Etot) {
  __shared__ int tmp[256];
  __shared__ int offs;
  int t = threadIdx.x;
  int v0 = (t < nb) ? bsum[t] : 0;
  tmp[t] = v0;
  __syncthreads();
  for (int off = 1; off < 256; off <<= 1) {
    int u = (t >= off) ? tmp[t - off] : 0;
    __syncthreads();
    tmp[t] += u;
    __syncthreads();
  }
  if (t == (int)blockIdx.x) offs = tmp[t] - v0;
  __syncthreads();
  int i = blockIdx.x * 256 + t;
  if (i < N) {
    int r = local[i] + offs;
    rowptr[i] = r;
    cursor[i] = r;
  }
  if (i == 0) rowptr[N] = Etot;
}

// ---------- layer-1 MFMA GEMM (permuted coalesced h1 stores) + csr_fill ----------
__global__ __launch_bounds__(256) void gemm1_fill_kernel(
    const unsigned short* __restrict__ xbf,     // N x 128 bf16
    const unsigned short* __restrict__ W1frag,  // [32][4][64][8] bf16
    const float* __restrict__ att_src,          // 512
    const float* __restrict__ att_dst,
    unsigned short* __restrict__ h1,            // N x 512 bf16 (PERMUTED)
    float* __restrict__ a_s, float* __restrict__ a_d,   // N x 8
    const int* __restrict__ ei, int E, int Etot,
    int* __restrict__ cursor, int* __restrict__ col,
    int gb, int N) {
  __shared__ __align__(16) unsigned short Xls[64 * 136];
  int t = threadIdx.x;

  if ((int)blockIdx.x >= gb) {                  // csr_fill blocks
    int e = ((int)blockIdx.x - gb) * 256 + t;
    if (e < Etot) {
      int s, d;
      if (e < E) { s = ei[e]; d = ei[E + e]; } else { s = d = e - E; }
      int pos = atomicAdd(&cursor[d], 1);
      col[pos] = s;
    }
    return;
  }

  int w = t >> 6, lane = t & 63;
  int quad = lane >> 4, l16 = lane & 15;
  int blkbase = blockIdx.x * 64;
  int rowbase = blkbase + w * 16;

  for (int idx = t; idx < 1024; idx += 256) {
    int row = idx >> 4, c = idx & 15;
    int rg = blkbase + row; if (rg >= N) rg = N - 1;
    *(uint4*)&Xls[row * 136 + c * 8] =
        *(const uint4*)(xbf + (size_t)rg * 128 + c * 8);
  }
  __syncthreads();

  short8 afr[4];
  {
    int rl = w * 16 + l16;
#pragma unroll
    for (int ks = 0; ks < 4; ++ks)
      afr[ks] = *(const short8*)&Xls[rl * 136 + ks * 32 + quad * 8];
  }

  for (int hp = 0; hp < 4; ++hp) {
    floatx4 acc[8] = {};
    const unsigned short* Bp = W1frag + (size_t)hp * 16384;
#pragma unroll
    for (int nt = 0; nt < 8; ++nt)
#pragma unroll
      for (int ks = 0; ks < 4; ++ks) {
        short8 b = *(const short8*)&Bp[((nt * 4 + ks) * 64 + lane) * 8];
        acc[nt] = __builtin_amdgcn_mfma_f32_16x16x32_bf16(afr[ks], b, acc[nt], 0, 0, 0);
      }

    // attention coefs (natural channel indexing, from registers)
    float asw[8], adw[8];
#pragma unroll
    for (int nt = 0; nt < 8; ++nt) {
      asw[nt] = att_src[hp * 128 + nt * 16 + l16];
      adw[nt] = att_dst[hp * 128 + nt * 16 + l16];
    }
    float ps[2][4] = {}, pd[2][4] = {};
#pragma unroll
    for (int nt = 0; nt < 8; ++nt) {
      int hl = nt >> 2;
#pragma unroll
      for (int r = 0; r < 4; ++r) {
        ps[hl][r] += acc[nt][r] * asw[nt];
        pd[hl][r] += acc[nt][r] * adw[nt];
      }
    }
#pragma unroll
    for (int hl = 0; hl < 2; ++hl)
#pragma unroll
      for (int r = 0; r < 4; ++r) {
        float p = ps[hl][r], q = pd[hl][r];
#pragma unroll
        for (int off = 1; off < 16; off <<= 1) {
          p += __shfl_xor(p, off);
          q += __shfl_xor(q, off);
        }
        int row = rowbase + quad * 4 + r;
        if (l16 == 0 && row < N) {
          a_s[(size_t)row * 8 + hp * 2 + hl] = p;
          a_d[(size_t)row * 8 + hp * 2 + hl] = q;
        }
      }

    // PERMUTED coalesced h1 stores: one uint4 per (lane, r) from registers.
    // Per store instr: 4 rows x 256B contiguous segments — fully coalesced.
#pragma unroll
    for (int r = 0; r < 4; ++r) {
      int row = rowbase + quad * 4 + r;
      if (row < N) {
        uint4 o;
        o.x = pack2(acc[0][r], acc[1][r]);
        o.y = pack2(acc[2][r], acc[3][r]);
        o.z = pack2(acc[4][r], acc[5][r]);
        o.w = pack2(acc[6][r], acc[7][r]);
        *(uint4*)&h1[(size_t)row * 512 + hp * 128 + l16 * 8] = o;
      }
    }
  }
}

// ---------- layer 2: MFMA bf16 GEMM (k-dim permuted to match out1bf) ----------
__global__ __launch_bounds__(256) void gemm2_mfma_kernel(
    const unsigned short* __restrict__ x2bf,    // N x 512 bf16 (PERMUTED k)
    const unsigned short* __restrict__ W2frag,  // [16ks][4nt][64][8] bf16 (perm k)
    const float* __restrict__ att_src,          // 64
    const float* __restrict__ att_dst,
    unsigned short* __restrict__ h2,            // N x 64 bf16 (natural)
    float* __restrict__ a_s, float* __restrict__ a_d,  // N
    int N) {
  int t = threadIdx.x;
  int w = t >> 6, lane = t & 63;
  int quad = lane >> 4, l16 = lane & 15;
  int rowbase = blockIdx.x * 64 + w * 16;

  floatx4 acc[4] = {};
  int r0 = rowbase + l16; if (r0 >= N) r0 = N - 1;
  const unsigned short* p0 = x2bf + (size_t)r0 * 512 + quad * 8;
#pragma unroll
  for (int ks = 0; ks < 16; ++ks) {
    short8 a0 = *(const short8*)(p0 + ks * 32);
#pragma unroll
    for (int nt = 0; nt < 4; ++nt) {
      short8 b = *(const short8*)&W2frag[((ks * 4 + nt) * 64 + lane) * 8];
      acc[nt] = __builtin_amdgcn_mfma_f32_16x16x32_bf16(a0, b, acc[nt], 0, 0, 0);
    }
  }

  float asw[4], adw[4];
#pragma unroll
  for (int nt = 0; nt < 4; ++nt) {
    asw[nt] = att_src[nt * 16 + l16];
    adw[nt] = att_dst[nt * 16 + l16];
  }
  float ps[4] = {}, pd[4] = {};
#pragma unroll
  for (int nt = 0; nt < 4; ++nt)
#pragma unroll
    for (int r = 0; r < 4; ++r) {
      float v = acc[nt][r];
      int row = rowbase + quad * 4 + r;
      if (row < N) h2[(size_t)row * 64 + nt * 16 + l16] = f2bbits(v);
      ps[r] += v * asw[nt];
      pd[r] += v * adw[nt];
    }
#pragma unroll
  for (int r = 0; r < 4; ++r) {
    float p = ps[r], q = pd[r];
#pragma unroll
    for (int off = 1; off < 16; off <<= 1) {
      p += __shfl_xor(p, off);
      q += __shfl_xor(q, off);
    }
    int row = rowbase + quad * 4 + r;
    if (l16 == 0 && row < N) {
      a_s[row] = p;
      a_d[row] = q;
    }
  }
}

// ---------- single-pass GAT aggregation, H=8, permuted h1 layout ----------
// Lane reads positions lane*8..+7: j=0..3 -> head (lane>>4)*2, j=4..7 -> +1.
__global__ void gat_agg8_kernel(const int* __restrict__ rowptr,
                                const int* __restrict__ col,
                                const float* __restrict__ a_s,
                                const float* __restrict__ a_d,
                                const unsigned short* __restrict__ hfeat,
                                const float* __restrict__ bias,   // PERMUTED
                                unsigned short* __restrict__ out, int N) {
  int wave = threadIdx.x >> 6, lane = threadIdx.x & 63;
  int d = blockIdx.x * 4 + wave;
  if (d >= N) return;
  int beg = rowptr[d], end = rowptr[d + 1];
  int hh0 = (lane >> 4) * 2, hh1 = hh0 + 1;
  float adh0 = a_d[(size_t)d * 8 + hh0];
  float adh1 = a_d[(size_t)d * 8 + hh1];

  const uint4* hf = (const uint4*)hfeat;
  float acc[8] = {};
  float ws0 = 0.f, ws1 = 0.f;
#pragma unroll 4
  for (int i = beg; i < end; ++i) {
    int s = col[i];                          // wave-uniform
    float e0 = a_s[(size_t)s * 8 + hh0] + adh0;
    e0 = e0 > 0.f ? e0 : NEG * e0;
    float w0 = __expf(e0);
    float e1 = a_s[(size_t)s * 8 + hh1] + adh1;
    e1 = e1 > 0.f ? e1 : NEG * e1;
    float w1 = __expf(e1);
    ws0 += w0; ws1 += w1;
    uint4 q = hf[(size_t)s * 64 + lane];
    acc[0] += w0 * blo(q.x); acc[1] += w0 * bhi(q.x);
    acc[2] += w0 * blo(q.y); acc[3] += w0 * bhi(q.y);
    acc[4] += w1 * blo(q.z); acc[5] += w1 * bhi(q.z);
    acc[6] += w1 * blo(q.w); acc[7] += w1 * bhi(q.w);
  }
  float wi0 = 1.f / (ws0 + 1e-16f), wi1 = 1.f / (ws1 + 1e-16f);
  const float4* b4 = (const float4*)bias;
  float4 b0 = b4[2 * lane], b1 = b4[2 * lane + 1];
  float v0 = elu1(acc[0] * wi0 + b0.x), v1 = elu1(acc[1] * wi0 + b0.y);
  float v2 = elu1(acc[2] * wi0 + b0.z), v3 = elu1(acc[3] * wi0 + b0.w);
  float v4 = elu1(acc[4] * wi1 + b1.x), v5 = elu1(acc[5] * wi1 + b1.y);
  float v6 = elu1(acc[6] * wi1 + b1.z), v7 = elu1(acc[7] * wi1 + b1.w);
  uint4 o;
  o.x = pack2(v0, v1); o.y = pack2(v2, v3);
  o.z = pack2(v4, v5); o.w = pack2(v6, v7);
  ((uint4*)out)[(size_t)d * 64 + lane] = o;   // positions 8*lane..+7 (permuted)
}

// H=1, quarter-wave edge grouping (h2 natural layout).
__global__ void gat_agg1_kernel(const int* __restrict__ rowptr,
                                const int* __restrict__ col,
                                const float* __restrict__ a_s,
                                const float* __restrict__ a_d,
                                const unsigned short* __restrict__ hfeat,
                                const float* __restrict__ bias,
                                unsigned short* __restrict__ out, int N) {
  int wave = threadIdx.x >> 6, lane = threadIdx.x & 63;
  int d = blockIdx.x * 4 + wave;
  if (d >= N) return;
  int beg = rowptr[d], end = rowptr[d + 1];
  int qg = lane >> 4, l16 = lane & 15;
  float adv = a_d[d];
  const uint2* hfu = (const uint2*)hfeat;
  float acc[4] = {};
  float wsum = 0.f;
#pragma unroll 2
  for (int i = beg + qg; i < end; i += 4) {
    int s = col[i];
    float v = a_s[s] + adv;
    v = v > 0.f ? v : NEG * v;
    float wv = __expf(v);
    wsum += wv;
    uint2 u = hfu[(size_t)s * 16 + l16];
    acc[0] += wv * blo(u.x); acc[1] += wv * bhi(u.x);
    acc[2] += wv * blo(u.y); acc[3] += wv * bhi(u.y);
  }
#pragma unroll
  for (int off = 16; off <= 32; off <<= 1) {
#pragma unroll
    for (int j = 0; j < 4; ++j) acc[j] += __shfl_xor(acc[j], off);
    wsum += __shfl_xor(wsum, off);
  }
  float winv = 1.f / (wsum + 1e-16f);
  float4 bb = ((const float4*)bias)[l16];
  float r0 = elu1(acc[0] * winv + bb.x), r1 = elu1(acc[1] * winv + bb.y);
  float r2 = elu1(acc[2] * winv + bb.z), r3 = elu1(acc[3] * winv + bb.w);
  if (qg == 0) {
    uint2 o; o.x = pack2(r0, r1); o.y = pack2(r2, r3);
    ((uint2*)out)[(size_t)d * 16 + l16] = o;
  }
}

// ---------- pooling: 16 nodes per wave ----------
__global__ void pool_kernel(const unsigned short* __restrict__ out2,
                            const int* __restrict__ batch,
                            float* __restrict__ pooled, int N) {
  int wave = threadIdx.x >> 6, lane = threadIdx.x & 63;
  int seg = blockIdx.x * 4 + wave;
  int start = seg * 16;
  if (start >= N) return;
  int end = min(start + 16, N);
  int cur = batch[start];
  float acc = 0.f;
  for (int n = start; n < end; ++n) {
    int bn = batch[n];
    if (bn != cur) {
      unsafeAtomicAdd(&pooled[cur * 64 + lane], acc);
      acc = 0.f; cur = bn;
    }
    acc += bu(out2[(size_t)n * 64 + lane]);
  }
  unsafeAtomicAdd(&pooled[cur * 64 + lane], acc);
}

// ---------- MLP head + log_softmax: one block (one wave) per graph ----------
__global__ void head_kernel(const float* __restrict__ pooled,
                            const float* __restrict__ lin1_w,
                            const float* __restrict__ lin1_b,
                            const float* __restrict__ lin2_w,
                            const float* __restrict__ lin2_b,
                            const void* __restrict__ x_raw,
                            void* __restrict__ outv) {
  __shared__ float P[C];
  __shared__ float Zs[C];
  __shared__ float Ls[K];
  __shared__ float lse_s;
  __shared__ int fl;
  int isbf = detect_dev(x_raw, &fl);
  int g = blockIdx.x, t = threadIdx.x;   // 64 threads
  P[t] = pooled[g * C + t];
  __syncthreads();
  float acc = lin1_b[t];
  for (int k = 0; k < C; ++k) acc += P[k] * lin1_w[k * C + t];
  Zs[t] = elu1(acc);
  __syncthreads();
  if (t < K) {
    float a = lin2_b[t];
    for (int k = 0; k < C; ++k) a += Zs[k] * lin2_w[k * K + t];
    Ls[t] = a;
  }
  __syncthreads();
  if (t == 0) {
    float mx = -1e30f;
    for (int c = 0; c < K; ++c) mx = fmaxf(mx, Ls[c]);
    float s = 0.f;
    for (int c = 0; c < K; ++c) s += __expf(Ls[c] - mx);
    lse_s = mx + __logf(s);
  }
  __syncthreads();
  if (t < K) {
    float val = Ls[t] - lse_s;
    if (isbf) ((__hip_bfloat16*)outv)[g * K + t] = __float2bfloat16(val);
    else      ((float*)outv)[g * K + t] = val;
  }
}

extern "C" void kernel_launch(void* const* d_in, const int* in_sizes, int n_in,
                              void* d_out, int out_size, void* d_ws, size_t ws_size,
                              hipStream_t stream) {
  const void* x_raw = d_in[0];
  const int*  ei    = (const int*)d_in[1];
  const int*  batch = (const int*)d_in[2];

  const int N    = in_sizes[2];
  const int E    = in_sizes[1] / 2;
  const int Etot = E + N;
  const int nb   = (N + 255) / 256;

  float* ws   = (float*)d_ws;
  size_t off  = 0;

  float* wts = ws + off; off += 6544;
  float* as1w = wts + 0;
  float* ad1w = wts + 512;
  float* b1w  = wts + 1024;
  float* as2w = wts + 1536;
  float* ad2w = wts + 1600;
  float* b2w  = wts + 1664;
  float* l1w  = wts + 1728;
  float* l1b  = wts + 5824;
  float* l2w  = wts + 5888;
  float* l2b  = wts + 6528;

  unsigned short* xbf    = (unsigned short*)(ws + off); off += (size_t)N * 64;
  unsigned short* w1frag = (unsigned short*)(ws + off); off += 32768;
  unsigned short* w2frag = (unsigned short*)(ws + off); off += 16384;
  unsigned short* h1bf   = (unsigned short*)(ws + off); off += (size_t)N * 256;
  unsigned short* out1bf = (unsigned short*)(ws + off); off += (size_t)N * 256;
  unsigned short* h2bf   = (unsigned short*)(ws + off); off += (size_t)N * 32;
  unsigned short* out2bf = (unsigned short*)(ws + off); off += (size_t)N * 32;
  float* as1  = ws + off; off += (size_t)N * H1;
  float* ad1  = ws + off; off += (size_t)N * H1;
  float* as2  = ws + off; off += (size_t)N;
  float* ad2  = ws + off; off += (size_t)N;
  float* pooled = ws + off; off += (size_t)B * C;

  int* ibase  = (int*)(ws + off);
  int* deg    = ibase;                 ibase += N;
  int* cursor = ibase;                 ibase += N;
  int* rowptr = ibase;                 ibase += N + 1;
  int* locals = ibase;                 ibase += N;
  int* bsum   = ibase;                 ibase += 256;
  int* col    = ibase;                 ibase += Etot;

  // ---- prep ----
  fused_prep_kernel<<<1024, 256, 0, stream>>>(
      x_raw, d_in[3], d_in[4], d_in[5], d_in[6], d_in[7], d_in[8], d_in[9],
      d_in[10], d_in[11], d_in[12], d_in[13], d_in[14],
      xbf, w1frag, w2frag, wts, deg, pooled, in_sizes[0], N);

  // ---- CSR: deg + scans ----
  deg_count_kernel<<<(Etot + 255) / 256, 256, 0, stream>>>(ei, E, Etot, deg);
  scan_block_kernel<<<nb, 256, 0, stream>>>(deg, locals, bsum, N);
  scan_finish_kernel<<<nb, 256, 0, stream>>>(locals, bsum, nb, rowptr, cursor, N, Etot);

  // ---- layer-1 GEMM + csr_fill (one dispatch, independent halves) ----
  {
    int gb = (N + 63) / 64;
    int fb = (Etot + 255) / 256;
    gemm1_fill_kernel<<<gb + fb, 256, 0, stream>>>(xbf, w1frag, as1w, ad1w,
                                                   h1bf, as1, ad1,
                                                   ei, E, Etot, cursor, col, gb, N);
  }

  // ---- layer 1 aggregation ----
  gat_agg8_kernel<<<(N + 3) / 4, 256, 0, stream>>>(rowptr, col, as1, ad1, h1bf, b1w, out1bf, N);

  // ---- layer 2 ----
  gemm2_mfma_kernel<<<(N + 63) / 64, 256, 0, stream>>>(out1bf, w2frag, as2w, ad2w,
                                                       h2bf, as2, ad2, N);
  gat_agg1_kernel<<<(N + 3) / 4, 256, 0, stream>>>(rowptr, col, as2, ad2, h2bf, b2w, out2bf, N);

  // ---- pool + head ----
  pool_kernel<<<(N + 63) / 64, 256, 0, stream>>>(out2bf, batch, pooled, N);
  head_kernel<<<B, 64, 0, stream>>>(pooled, l1w, l1b, l2w, l2b, x_raw, (void*)d_out);
}